// Round 7
// baseline (360.441 us; speedup 1.0000x reference)
//
#include <hip/hip_runtime.h>

typedef unsigned short u16;
typedef unsigned char u8;
typedef long i64;
typedef __attribute__((ext_vector_type(8))) short bf16x8;
typedef __attribute__((ext_vector_type(4))) float f32x4;
typedef __attribute__((ext_vector_type(8))) u16 u16x8;
typedef __attribute__((ext_vector_type(4))) u16 u16x4;
typedef __attribute__((ext_vector_type(4))) float f4;

#define DEVI static __device__ __forceinline__

DEVI u16 f2b(float f) { __bf16 h = (__bf16)f; return __builtin_bit_cast(u16, h); }
DEVI float b2f(u16 h) { unsigned u = ((unsigned)h) << 16; return __builtin_bit_cast(float, u); }

DEVI int pk8(float a, float b, float c, float d) {
  int w = __builtin_amdgcn_cvt_pk_fp8_f32(a, b, 0, false);
  return __builtin_amdgcn_cvt_pk_fp8_f32(c, d, w, true);
}

DEVI void gload16(const void* g, void* l) {
  __builtin_amdgcn_global_load_lds((const __attribute__((address_space(1))) void*)g,
                                   (__attribute__((address_space(3))) void*)l, 16, 0, 0);
}

// ---------------------------------------------------------------------------
// FUSED layer-1 big GEMM + f32->fp8 conversion with side-copy.
// 1024 threads = 16 waves (4/SIMD), wave tile 32x64, 4 LDS buffers,
// ONE raw s_barrier per tile, two rA parity banks.
// vmcnt ladder (per-wave queue = [loads(t)=3, stores(t-1)=2, loads(t+1)=3]):
//   t==0: vmcnt(3)  (no stores in queue yet; drain loads(0))
//   else: vmcnt(5)  (drain loads(t) ONLY -- side-copy stores age out later,
//                    their ~900cy ack latency stays OFF the critical path)
//   last: vmcnt(0)
//   C[M,256] = A0f32[M,K0]@B0^T + A1f32[M,K1]@B1^T, partials to Cout + z*MN.
// BM=128, BN=256 (each A elem read exactly once), BK=64. A loads nontemporal.
// ---------------------------------------------------------------------------
__global__ __launch_bounds__(1024)
void gemmF_k(const float* __restrict__ A0, const float* __restrict__ A1,
             const u8* __restrict__ B0, const u8* __restrict__ B1,
             u8* __restrict__ A0f8, u8* __restrict__ A1f8,
             int K0, int K1, int L0, int L1,
             float* __restrict__ Cout, size_t MN)
{
  constexpr int BM = 128, BK = 64;
  constexpr int LDA = 72;
  constexpr int ASZ = BM * LDA;     // 9216
  constexpr int BSZ = 256 * BK;     // 16384
  constexpr int BUFSZ = ASZ + BSZ;  // 25600
  constexpr float SADJ = 8192.f;
  __shared__ __align__(16) u8 lds[4 * BUFSZ];   // 100 KiB -> 1 block/CU

  const int tid = threadIdx.x, lane = tid & 63, wave = tid >> 6;
  const int wm = (wave >> 2) * 32, wn = (wave & 3) * 64;   // 4x4 wave grid
  const int lgrp = lane >> 4, lrow = lane & 15;

  // XCD-chunked bijective swizzle (nwg % 8 == 0)
  const int gy = gridDim.y;
  const int flat = blockIdx.y + gy * blockIdx.z;
  const int nwg = gy * gridDim.z;
  const int swz = (flat & 7) * (nwg >> 3) + (flat >> 3);
  const int m0 = (swz % gy) * BM;
  const int z  = swz / gy;

  const int nt0 = L0 >> 6, NT = nt0 + (L1 >> 6);   // even for our KS choices

  const int r0 = tid >> 4;           // 0..63
  const int cf = (tid & 15) << 2;    // 0..60

  f32x4 acc[2][4];
#pragma unroll
  for (int m = 0; m < 2; ++m)
#pragma unroll
    for (int n = 0; n < 4; ++n) acc[m][n] = (f32x4){0.f, 0.f, 0.f, 0.f};

  f4 rA0[2], rA1[2];   // two parity banks of in-flight A f32 rows

  auto tileinfo = [&](int t, const float*& Ap, const u8*& Bp, u8*& Af8, int& Kj, int& kk) {
    if (t < nt0) { Ap = A0; Bp = B0; Af8 = A0f8; Kj = K0; kk = z * L0 + (t << 6); }
    else         { Ap = A1; Bp = B1; Af8 = A1f8; Kj = K1; kk = z * L1 + ((t - nt0) << 6); }
  };

  auto loadA = [&](int t, f4 (&r)[2]) {
    const float* Ap; const u8* Bp; u8* Af8; int Kj, kk;
    tileinfo(t, Ap, Bp, Af8, Kj, kk);
#pragma unroll
    for (int j = 0; j < 2; ++j) {
      const int rr = j * 64 + r0;
      r[j] = __builtin_nontemporal_load(
          (const f4*)(Ap + (size_t)(m0 + rr) * Kj + kk + cf));
    }
  };

  auto loadB = [&](int t) {
    const float* Ap; const u8* Bp; u8* Af8; int Kj, kk;
    tileinfo(t, Ap, Bp, Af8, Kj, kk);
    u8* sB = &lds[(t & 3) * BUFSZ] + ASZ;
    const int off = tid * 16;                 // 1024 thr x 16B = 16 KiB tile
    const int r = off >> 6, c = off & 63;
    gload16(Bp + (size_t)r * Kj + kk + (c ^ (((r >> 1) & 3) << 4)), sB + off);
  };

  auto writeA = [&](int t, f4 (&r)[2]) {  // consume r: cvt + ds_write + side-store
    const float* Ap; const u8* Bp; u8* Af8; int Kj, kk;
    tileinfo(t, Ap, Bp, Af8, Kj, kk);
    u8* sA = &lds[(t & 3) * BUFSZ];
#pragma unroll
    for (int j = 0; j < 2; ++j) {
      const int rr = j * 64 + r0;
      const int pw = pk8(r[j][0] * SADJ, r[j][1] * SADJ, r[j][2] * SADJ, r[j][3] * SADJ);
      *(int*)&sA[rr * LDA + cf] = pw;
      *(int*)(Af8 + (size_t)(m0 + rr) * Kj + kk + cf) = pw;
    }
  };

  auto compute = [&](int t) {
    const u8* sA = &lds[(t & 3) * BUFSZ];
    const u8* sB = sA + ASZ;
#pragma unroll
    for (int ks = 0; ks < 2; ++ks) {
      i64 a[2], b[4];
#pragma unroll
      for (int m = 0; m < 2; ++m) {
        const int r = wm + m * 16 + lrow;
        a[m] = *(const i64*)&sA[r * LDA + ks * 32 + lgrp * 8];
      }
#pragma unroll
      for (int n = 0; n < 4; ++n) {
        const int r = wn + n * 16 + lrow;
        b[n] = *(const i64*)&sB[r * BK + ((ks * 32 + lgrp * 8) ^ (((r >> 1) & 3) << 4))];
      }
#pragma unroll
      for (int m = 0; m < 2; ++m)
#pragma unroll
        for (int n = 0; n < 4; ++n)
          acc[m][n] = __builtin_amdgcn_mfma_f32_16x16x32_fp8_fp8(a[m], b[n], acc[m][n], 0, 0, 0);
    }
  };

  auto step = [&](int t, f4 (&rIn)[2], f4 (&rOut)[2]) {
    const bool has_next = (t + 1 < NT);
    if (has_next) { loadA(t + 1, rOut); loadB(t + 1); }   // issue early
    if (!has_next)   asm volatile("s_waitcnt vmcnt(0)" ::: "memory");
    else if (t == 0) asm volatile("s_waitcnt vmcnt(3)" ::: "memory");
    else             asm volatile("s_waitcnt vmcnt(5)" ::: "memory");  // loads(t) only
    writeA(t, rIn);
    asm volatile("s_waitcnt lgkmcnt(0)" ::: "memory");   // ds_writes visible
    asm volatile("s_barrier" ::: "memory");              // raw: loads/stores stay in flight
    compute(t);
  };

  // prologue
  loadA(0, rA0); loadB(0);

  for (int t = 0; t < NT; t += 2) {
    step(t, rA0, rA1);
    step(t + 1, rA1, rA0);
  }

  float* Cp = Cout + (size_t)z * MN;
#pragma unroll
  for (int n = 0; n < 4; ++n) {
    const int c = wn + n * 16 + lrow;
#pragma unroll
    for (int m = 0; m < 2; ++m) {
      const int rb = m0 + wm + m * 16 + lgrp * 4;
#pragma unroll
      for (int q = 0; q < 4; ++q)
        Cp[(size_t)(rb + q) * 256 + c] = acc[m][n][q];
    }
  }
}

// ---------------------------------------------------------------------------
// fp8 big GEMM (layer-2), depth-2 counted-vmcnt pipeline, 3 LDS buffers.
// Per-thread ops/stage = 6 (4 A + 2 B gload16). Steady wait vmcnt(6)
// (= loads(t+1) outstanding, drain loads(t)); raw s_barrier (no drain).
// stage(t+2) writes buf(t-1)%3 whose last reader compute(t-1) finished
// before the barrier just passed -> race-free.
// ---------------------------------------------------------------------------
template<int BN>
__global__ __launch_bounds__(256)
void gemm8_k(const u8* __restrict__ A0, const u8* __restrict__ A1,
             const u8* __restrict__ B0, const u8* __restrict__ B1,
             int K0, int K1, int L0, int L1,
             float* __restrict__ Cout, int N, size_t MN)
{
  constexpr int BM = 128, BK = 128;
  constexpr int MR = 4, NR = BN / 32;
  constexpr int ASZ = BM * BK, BSZ = BN * BK;
  __shared__ __align__(16) u8 lds[3 * (ASZ + BSZ)];

  const int tid = threadIdx.x, lane = tid & 63, wave = tid >> 6;
  const int wm = (wave >> 1) * 64, wn = (wave & 1) * (BN / 2);
  const int lgrp = lane >> 4, lrow = lane & 15;

  const int gx = gridDim.x, gy = gridDim.y;
  const int flat = blockIdx.x + gx * (blockIdx.y + gy * blockIdx.z);
  const int nwg = gx * gy * gridDim.z;
  const int swz = (flat & 7) * (nwg >> 3) + (flat >> 3);
  const int n0 = (swz % gx) * BN;
  const int m0 = ((swz / gx) % gy) * BM;
  const int z  = swz / (gx * gy);

  const int nt0 = L0 >> 7, NT = nt0 + (L1 >> 7);

  f32x4 acc[MR][NR];
#pragma unroll
  for (int m = 0; m < MR; ++m)
#pragma unroll
    for (int n = 0; n < NR; ++n) acc[m][n] = (f32x4){0.f, 0.f, 0.f, 0.f};

  auto stage = [&](int buf, int t) {
    const u8* Ap; const u8* Bp; int Kj, kk;
    if (t < nt0) { Ap = A0; Bp = B0; Kj = K0; kk = z * L0 + (t << 7); }
    else         { Ap = A1; Bp = B1; Kj = K1; kk = z * L1 + ((t - nt0) << 7); }
    u8* sA = &lds[buf * (ASZ + BSZ)];
    u8* sB = sA + ASZ;
#pragma unroll
    for (int i = 0; i < ASZ / 4096; ++i) {
      const int off = i * 4096 + tid * 16;
      const int r = off >> 7, c = off & 127;
      gload16(Ap + (size_t)(m0 + r) * Kj + kk + (c ^ ((r & 7) << 4)), sA + off);
    }
#pragma unroll
    for (int i = 0; i < BSZ / 4096; ++i) {
      const int off = i * 4096 + tid * 16;
      const int r = off >> 7, c = off & 127;
      gload16(Bp + (size_t)(n0 + r) * Kj + kk + (c ^ ((r & 7) << 4)), sB + off);
    }
  };

  auto compute = [&](int buf) {
    const u8* sA = &lds[buf * (ASZ + BSZ)];
    const u8* sB = sA + ASZ;
#pragma unroll
    for (int ks = 0; ks < 4; ++ks) {
      i64 a[MR], b[NR];
#pragma unroll
      for (int m = 0; m < MR; ++m) {
        const int r = wm + m * 16 + lrow;
        a[m] = *(const i64*)&sA[r * BK + ((ks * 32 + lgrp * 8) ^ ((r & 7) << 4))];
      }
#pragma unroll
      for (int n = 0; n < NR; ++n) {
        const int r = wn + n * 16 + lrow;
        b[n] = *(const i64*)&sB[r * BK + ((ks * 32 + lgrp * 8) ^ ((r & 7) << 4))];
      }
#pragma unroll
      for (int m = 0; m < MR; ++m)
#pragma unroll
        for (int n = 0; n < NR; ++n)
          acc[m][n] = __builtin_amdgcn_mfma_f32_16x16x32_fp8_fp8(a[m], b[n], acc[m][n], 0, 0, 0);
    }
  };

  stage(0, 0);
  stage(1, 1);
  for (int t = 0; t < NT; ++t) {
    if (t + 1 < NT) asm volatile("s_waitcnt vmcnt(6)" ::: "memory");  // drain loads(t)
    else            asm volatile("s_waitcnt vmcnt(0)" ::: "memory");
    asm volatile("s_barrier" ::: "memory");
    compute(t % 3);
    if (t + 2 < NT) stage((t + 2) % 3, t + 2);
  }

  float* Cp = Cout + (size_t)z * MN;
#pragma unroll
  for (int n = 0; n < NR; ++n) {
    const int c = n0 + wn + n * 16 + lrow;
#pragma unroll
    for (int m = 0; m < MR; ++m) {
      const int rb = m0 + wm + m * 16 + lgrp * 4;
#pragma unroll
      for (int q = 0; q < 4; ++q)
        Cp[(size_t)(rb + q) * N + c] = acc[m][n][q];
    }
  }
}

// ---------------------------------------------------------------------------
// Generic tiled bf16 MFMA GEMM (smalls + h_hat).
// EPI 2: fp8 C^T * sOut, dual output split at nsplit rows of C^T.
// EPI 3: sigmoid -> f32 row-major.
// ---------------------------------------------------------------------------
template<int BM, int BN, bool A_F32, int EPI>
__global__ __launch_bounds__(256)
void gemm_k(const void* A0_, const u16* B0_, int K0,
            void* Cout, void* Cout2, int nsplit, int ldc, float sOut)
{
  constexpr int BK = 32;
  constexpr int LD = 40;
  constexpr int MR = BM / 32;
  constexpr int NR = BN / 32;
  __shared__ u16 sA[BM * LD];
  __shared__ u16 sB[BN * LD];

  const int tid  = threadIdx.x;
  const int lane = tid & 63;
  const int wave = tid >> 6;
  const int wm = (wave >> 1) * (BM / 2);
  const int wn = (wave &  1) * (BN / 2);
  const int m0 = blockIdx.y * BM;
  const int n0 = blockIdx.x * BN;

  constexpr int TPRA = 256 / BM;
  constexpr int EPTA = 32 / TPRA;
  constexpr int TPRB = 256 / BN;
  constexpr int EPTB = 32 / TPRB;
  const int ar = tid / TPRA, ac = (tid % TPRA) * EPTA;
  const int br = tid / TPRB, bc = (tid % TPRB) * EPTB;

  f32x4 acc[MR][NR];
#pragma unroll
  for (int m = 0; m < MR; ++m)
#pragma unroll
    for (int n = 0; n < NR; ++n) acc[m][n] = (f32x4){0.f, 0.f, 0.f, 0.f};

  const int lgrp = lane >> 4, lrow = lane & 15;

  for (int kk = 0; kk < K0; kk += BK) {
    if constexpr (A_F32) {
      const float* Ap = (const float*)A0_ + (size_t)(m0 + ar) * K0 + kk + ac;
#pragma unroll
      for (int q = 0; q < EPTA / 8; ++q) {
        f4 v0 = ((const f4*)Ap)[2 * q];
        f4 v1 = ((const f4*)Ap)[2 * q + 1];
        u16x8 h;
        h[0]=f2b(v0[0]); h[1]=f2b(v0[1]); h[2]=f2b(v0[2]); h[3]=f2b(v0[3]);
        h[4]=f2b(v1[0]); h[5]=f2b(v1[1]); h[6]=f2b(v1[2]); h[7]=f2b(v1[3]);
        *(u16x8*)&sA[ar * LD + ac + q * 8] = h;
      }
    } else {
      const u16* Ap = (const u16*)A0_ + (size_t)(m0 + ar) * K0 + kk + ac;
#pragma unroll
      for (int q = 0; q < EPTA / 8; ++q)
        *(u16x8*)&sA[ar * LD + ac + q * 8] = ((const u16x8*)Ap)[q];
    }
    {
      const u16* Bp = B0_ + (size_t)(n0 + br) * K0 + kk + bc;
#pragma unroll
      for (int q = 0; q < EPTB / 8; ++q)
        *(u16x8*)&sB[br * LD + bc + q * 8] = ((const u16x8*)Bp)[q];
    }
    __syncthreads();
    bf16x8 af[MR], bfr[NR];
#pragma unroll
    for (int m = 0; m < MR; ++m)
      af[m] = *(const bf16x8*)&sA[(wm + m * 16 + lrow) * LD + lgrp * 8];
#pragma unroll
    for (int n = 0; n < NR; ++n)
      bfr[n] = *(const bf16x8*)&sB[(wn + n * 16 + lrow) * LD + lgrp * 8];
#pragma unroll
    for (int m = 0; m < MR; ++m)
#pragma unroll
      for (int n = 0; n < NR; ++n)
        acc[m][n] = __builtin_amdgcn_mfma_f32_16x16x32_bf16(af[m], bfr[n], acc[m][n], 0, 0, 0);
    __syncthreads();
  }

  if constexpr (EPI == 2) {
#pragma unroll
    for (int n = 0; n < NR; ++n) {
      const int c = n0 + wn + n * 16 + lrow;
      u8* Cp = (c < nsplit) ? (u8*)Cout : (u8*)Cout2;
      const int cr = (c < nsplit) ? c : c - nsplit;
#pragma unroll
      for (int m = 0; m < MR; ++m) {
        const int rb = m0 + wm + m * 16 + lgrp * 4;
        int w = __builtin_amdgcn_cvt_pk_fp8_f32(acc[m][n][0] * sOut, acc[m][n][1] * sOut, 0, false);
        w = __builtin_amdgcn_cvt_pk_fp8_f32(acc[m][n][2] * sOut, acc[m][n][3] * sOut, w, true);
        *(int*)&Cp[(size_t)cr * ldc + rb] = w;
      }
    }
  } else {  // EPI == 3
    float* Cp = (float*)Cout;
#pragma unroll
    for (int n = 0; n < NR; ++n) {
      const int c = n0 + wn + n * 16 + lrow;
#pragma unroll
      for (int m = 0; m < MR; ++m) {
        const int rb = m0 + wm + m * 16 + lgrp * 4;
#pragma unroll
        for (int q = 0; q < 4; ++q)
          Cp[(size_t)(rb + q) * ldc + c] = 1.f / (1.f + __expf(-acc[m][n][q]));
      }
    }
  }
}

// out[i] = lrelu( invs*sum_z parts[z][i] + mix*b0[c] + (1-mix)*b1[c] ) -> bf16
__global__ __launch_bounds__(256)
void combine_k(const float* __restrict__ parts, int KS, int N, size_t MN,
               const float* b0, const float* b1, const float* mixp, u16* out, float invs)
{
  const float mix = *mixp;
  const size_t stride = (size_t)gridDim.x * 1024;
  for (size_t i = ((size_t)blockIdx.x * 256 + threadIdx.x) * 4; i < MN; i += stride) {
    f4 s = {0.f, 0.f, 0.f, 0.f};
    for (int zz = 0; zz < KS; ++zz)
      s += *(const f4*)&parts[(size_t)zz * MN + i];
    const int c = (int)(i % (size_t)N);
    u16x4 o;
#pragma unroll
    for (int q = 0; q < 4; ++q) {
      float v = s[q] * invs + mix * b0[c + q] + (1.f - mix) * b1[c + q];
      v = v >= 0.f ? v : 0.2f * v;
      o[q] = f2b(v);
    }
    *(u16x4*)&out[i] = o;
  }
}

// Concatenated transposed scaled bf16 weights:
// WtX[512][512] = [Wx1a*a ; Wy1b*(1-b)], WtY[512][256] = [Wx1b*(1-a) ; Wy1a*b]
// W2X[128][256] = [Wx2a*a ; Wy2b*(1-b)], W2Y[128][256] = [Wx2b*(1-a) ; Wy2a*b]
__global__ __launch_bounds__(256)
void prep_w(const float* Wx1a, const float* Wx1b, const float* Wy1a, const float* Wy1b,
            const float* Wx2a, const float* Wx2b, const float* Wy2a, const float* Wy2b,
            u16* WtX, u16* WtY, u16* W2X, u16* W2Y,
            const float* ap, const float* bp)
{
  const int zz = blockIdx.z;
  const float a = *ap, b = *bp;
  const float* W; u16* O; int K, N, roff; float s;
  switch (zz) {
    case 0: W=Wx1a; O=WtX; K=512; N=256; roff=0;   s=a;      break;
    case 1: W=Wy1b; O=WtX; K=512; N=256; roff=256; s=1.f-b;  break;
    case 2: W=Wx1b; O=WtY; K=256; N=256; roff=0;   s=1.f-a;  break;
    case 3: W=Wy1a; O=WtY; K=256; N=256; roff=256; s=b;      break;
    case 4: W=Wx2a; O=W2X; K=256; N=64;  roff=0;   s=a;      break;
    case 5: W=Wy2b; O=W2X; K=256; N=64;  roff=64;  s=1.f-b;  break;
    case 6: W=Wx2b; O=W2Y; K=256; N=64;  roff=0;   s=1.f-a;  break;
    default:W=Wy2a; O=W2Y; K=256; N=64;  roff=64;  s=b;      break;
  }
  const int total = K * N;
  for (int i = blockIdx.x * 256 + threadIdx.x; i < total; i += gridDim.x * 256) {
    const int k = i / N, n = i - k * N;
    O[(size_t)(n + roff) * K + k] = f2b(W[i] * s);
  }
}

__global__ __launch_bounds__(256)
void softmax_k(const u16* x, float* out)
{
  const int row  = blockIdx.x * 4 + (threadIdx.x >> 6);
  const int lane = threadIdx.x & 63;
  const float v = b2f(x[row * 64 + lane]);
  float m = v;
#pragma unroll
  for (int off = 32; off; off >>= 1) m = fmaxf(m, __shfl_xor(m, off));
  float s = __expf(v - m);
#pragma unroll
  for (int off = 32; off; off >>= 1) s += __shfl_xor(s, off);
  out[(size_t)row * 64 + lane] = v - m - __logf(s);
}

extern "C" void kernel_launch(void* const* d_in, const int* in_sizes, int n_in,
                              void* d_out, int out_size, void* d_ws, size_t ws_size,
                              hipStream_t stream)
{
  const float* hx1 = (const float*)d_in[0];
  const float* hx2 = (const float*)d_in[1];
  const float* x0  = (const float*)d_in[2];
  const float* hy1 = (const float*)d_in[3];
  const float* hy2 = (const float*)d_in[4];
  const float* y0  = (const float*)d_in[5];
  const float* alphap = (const float*)d_in[6];
  const float* betap  = (const float*)d_in[7];
  const float* Wx1a = (const float*)d_in[8];  const float* bx1a = (const float*)d_in[9];
  const float* Wx1b = (const float*)d_in[10]; const float* bx1b = (const float*)d_in[11];
  const float* Wx2a = (const float*)d_in[12]; const float* bx2a = (const float*)d_in[13];
  const float* Wx2b = (const float*)d_in[14]; const float* bx2b = (const float*)d_in[15];
  const float* Wy1a = (const float*)d_in[16]; const float* by1a = (const float*)d_in[17];
  const float* Wy1b = (const float*)d_in[18]; const float* by1b = (const float*)d_in[19];
  const float* Wy2a = (const float*)d_in[20]; const float* by2a = (const float*)d_in[21];
  const float* Wy2b = (const float*)d_in[22]; const float* by2b = (const float*)d_in[23];
  (void)in_sizes; (void)n_in; (void)out_size;

  constexpr int Nx = 8192, Ny = 4096, Fx = 512, Fy = 256, D1 = 256, C = 64;
  constexpr float SB1 = 16.f, SB2 = 256.f;
  constexpr float INV1 = 1.f / (8192.f * 16.f);
  constexpr float INV2 = 1.f / (8192.f * 256.f);
  constexpr int KSx = 4, KSy = 8;   // layer-1 K-splits (256-block grids, 1 blk/CU)

  u8* wsb = (u8*)d_ws;
  size_t off = 0;
  auto alloc = [&](size_t n) { u8* p = wsb + off; off += (n + 63) & ~(size_t)63; return p; };

  u16* WtX = (u16*)alloc((size_t)512 * 512 * 2);
  u16* WtY = (u16*)alloc((size_t)512 * 256 * 2);
  u16* W2X = (u16*)alloc((size_t)128 * 256 * 2);
  u16* W2Y = (u16*)alloc((size_t)128 * 256 * 2);
  u8* B1x  = alloc((size_t)D1 * Nx);
  u8* B2x  = alloc((size_t)D1 * Ny);
  u8* B1y  = alloc((size_t)D1 * Ny);
  u8* B2y  = alloc((size_t)D1 * Nx);
  u16* x1  = (u16*)alloc((size_t)Nx * D1 * 2);
  u16* y1  = (u16*)alloc((size_t)Ny * D1 * 2);
  u8* B1x2 = alloc((size_t)C * Nx);
  u8* B2x2 = alloc((size_t)C * Ny);
  u8* B1y2 = alloc((size_t)C * Ny);
  u8* B2y2 = alloc((size_t)C * Nx);
  u16* x2  = (u16*)alloc((size_t)Nx * C * 2);
  u16* y2  = (u16*)alloc((size_t)Ny * C * 2);

  const size_t base_off = off;
  const size_t szHx1 = (size_t)Nx * Nx, szHx2 = (size_t)Nx * Ny;
  const size_t szHy1 = (size_t)Ny * Ny, szHy2 = (size_t)Ny * Nx;
  const size_t needA = base_off + szHx1 + szHx2 + szHy1 + szHy2 + ((size_t)32 << 20) + (1 << 20);

  u8 *hx1f8, *hx2f8, *hy1f8, *hy2f8; float* part;
  if (ws_size >= needA) {
    hx1f8 = alloc(szHx1); hx2f8 = alloc(szHx2);
    hy1f8 = alloc(szHy1); hy2f8 = alloc(szHy2);
    part  = (float*)alloc((size_t)32 << 20);
  } else {
    hy1f8 = alloc(szHy1); hy2f8 = alloc(szHy2);
    hx1f8 = (u8*)d_out;
    hx2f8 = (u8*)d_out + szHx1;
    part  = (float*)((u8*)d_out + szHx1 + szHx2);   // 32 MiB region in d_out
  }

  const size_t MNx1 = (size_t)Nx * D1, MNy1 = (size_t)Ny * D1;
  const size_t MNx2 = (size_t)Nx * C,  MNy2 = (size_t)Ny * C;

  // 1) concat weights
  prep_w<<<dim3(256, 1, 8), 256, 0, stream>>>(Wx1a, Wx1b, Wy1a, Wy1b, Wx2a, Wx2b, Wy2a, Wy2b,
      WtX, WtY, W2X, W2Y, alphap, betap);

  // 2) layer-1 fused small pairs -> fp8 transposed B operands
  gemm_k<64,64,true,2><<<dim3(8, Nx/64), 256, 0, stream>>>(x0, WtX, Fx, B1x, B2y, 256, Nx, SB1);
  gemm_k<64,64,true,2><<<dim3(8, Ny/64), 256, 0, stream>>>(y0, WtY, Fy, B2x, B1y, 256, Ny, SB1);

  // 3) layer-1 FUSED big GEMMs (f32 A -> fp8 in-flight, side-copy for layer 2)
  gemmF_k<<<dim3(1, Nx/128, KSx), 1024, 0, stream>>>(hx1, hx2, B1x, B2x, hx1f8, hx2f8,
      Nx, Ny, Nx/KSx, Ny/KSx, part, MNx1);
  combine_k<<<dim3(2048), 256, 0, stream>>>(part, KSx, D1, MNx1, bx1a, bx1b, alphap, x1, INV1);
  gemmF_k<<<dim3(1, Ny/128, KSy), 1024, 0, stream>>>(hy1, hy2, B1y, B2y, hy1f8, hy2f8,
      Ny, Nx, Ny/KSy, Nx/KSy, part, MNy1);
  combine_k<<<dim3(1024), 256, 0, stream>>>(part, KSy, D1, MNy1, by1a, by1b, betap, y1, INV1);

  // 4) layer-2 fused small pairs (bf16 A)
  gemm_k<64,64,false,2><<<dim3(2, Nx/64), 256, 0, stream>>>(x1, W2X, D1, B1x2, B2y2, 64, Nx, SB2);
  gemm_k<64,64,false,2><<<dim3(2, Ny/64), 256, 0, stream>>>(y1, W2Y, D1, B2x2, B1y2, 64, Ny, SB2);

  // 5) layer-2 big GEMMs (fp8 copies, L3-resident)
  gemm8_k<64><<<dim3(1, 64, 8), 256, 0, stream>>>(hx1f8, hx2f8, B1x2, B2x2, Nx, Ny, 1024, 512, part, C, MNx2);
  combine_k<<<dim3(512), 256, 0, stream>>>(part, 8, C, MNx2, bx2a, bx2b, alphap, x2, INV2);
  gemm8_k<64><<<dim3(1, 32, 16), 256, 0, stream>>>(hy1f8, hy2f8, B1y2, B2y2, Ny, Nx, 256, 512, part, C, MNy2);
  combine_k<<<dim3(256), 256, 0, stream>>>(part, 16, C, MNy2, by2a, by2b, betap, y2, INV2);

  // 6) h_hat = sigmoid(x2 @ y2^T) -> d_out (overwrites scratch there)
  gemm_k<128,128,false,3><<<dim3(Ny/128, Nx/128), 256, 0, stream>>>(x2, y2, C, d_out, nullptr, 0, Ny, 1.f);

  // 7) x_output = log_softmax(x2)
  softmax_k<<<dim3(Nx/4), 256, 0, stream>>>(x2, (float*)d_out + (size_t)Nx * Ny);
}

// Round 8
// 344.997 us; speedup vs baseline: 1.0448x; 1.0448x over previous
//
#include <hip/hip_runtime.h>

typedef unsigned short u16;
typedef unsigned char u8;
typedef long i64;
typedef __attribute__((ext_vector_type(8))) short bf16x8;
typedef __attribute__((ext_vector_type(4))) float f32x4;
typedef __attribute__((ext_vector_type(8))) u16 u16x8;
typedef __attribute__((ext_vector_type(4))) u16 u16x4;
typedef __attribute__((ext_vector_type(4))) float f4;

#define DEVI static __device__ __forceinline__

DEVI u16 f2b(float f) { __bf16 h = (__bf16)f; return __builtin_bit_cast(u16, h); }
DEVI float b2f(u16 h) { unsigned u = ((unsigned)h) << 16; return __builtin_bit_cast(float, u); }

DEVI int pk8(float a, float b, float c, float d) {
  int w = __builtin_amdgcn_cvt_pk_fp8_f32(a, b, 0, false);
  return __builtin_amdgcn_cvt_pk_fp8_f32(c, d, w, true);
}

DEVI void gload16(const void* g, void* l) {
  __builtin_amdgcn_global_load_lds((const __attribute__((address_space(1))) void*)g,
                                   (__attribute__((address_space(3))) void*)l, 16, 0, 0);
}

// ---------------------------------------------------------------------------
// FUSED layer-1 big GEMM + f32->fp8 conversion with side-copy.
// Structure from R6/R7 (near its per-CU streaming roofline): 1024 threads,
// 16 waves, 4 LDS buffers, raw s_barrier/tile, vmcnt ladder 3/5/0.
// R8: bf16 partials (halves partial traffic), setprio around MFMA.
// ---------------------------------------------------------------------------
__global__ __launch_bounds__(1024)
void gemmF_k(const float* __restrict__ A0, const float* __restrict__ A1,
             const u8* __restrict__ B0, const u8* __restrict__ B1,
             u8* __restrict__ A0f8, u8* __restrict__ A1f8,
             int K0, int K1, int L0, int L1,
             u16* __restrict__ Cout, size_t MN)
{
  constexpr int BM = 128, BK = 64;
  constexpr int LDA = 72;
  constexpr int ASZ = BM * LDA;     // 9216
  constexpr int BSZ = 256 * BK;     // 16384
  constexpr int BUFSZ = ASZ + BSZ;  // 25600
  constexpr float SADJ = 8192.f;
  __shared__ __align__(16) u8 lds[4 * BUFSZ];   // 100 KiB -> 1 block/CU

  const int tid = threadIdx.x, lane = tid & 63, wave = tid >> 6;
  const int wm = (wave >> 2) * 32, wn = (wave & 3) * 64;   // 4x4 wave grid
  const int lgrp = lane >> 4, lrow = lane & 15;

  const int gy = gridDim.y;
  const int flat = blockIdx.y + gy * blockIdx.z;
  const int nwg = gy * gridDim.z;
  const int swz = (flat & 7) * (nwg >> 3) + (flat >> 3);
  const int m0 = (swz % gy) * BM;
  const int z  = swz / gy;

  const int nt0 = L0 >> 6, NT = nt0 + (L1 >> 6);

  const int r0 = tid >> 4;           // 0..63
  const int cf = (tid & 15) << 2;    // 0..60

  f32x4 acc[2][4];
#pragma unroll
  for (int m = 0; m < 2; ++m)
#pragma unroll
    for (int n = 0; n < 4; ++n) acc[m][n] = (f32x4){0.f, 0.f, 0.f, 0.f};

  f4 rA0[2], rA1[2];

  auto tileinfo = [&](int t, const float*& Ap, const u8*& Bp, u8*& Af8, int& Kj, int& kk) {
    if (t < nt0) { Ap = A0; Bp = B0; Af8 = A0f8; Kj = K0; kk = z * L0 + (t << 6); }
    else         { Ap = A1; Bp = B1; Af8 = A1f8; Kj = K1; kk = z * L1 + ((t - nt0) << 6); }
  };

  auto loadA = [&](int t, f4 (&r)[2]) {
    const float* Ap; const u8* Bp; u8* Af8; int Kj, kk;
    tileinfo(t, Ap, Bp, Af8, Kj, kk);
#pragma unroll
    for (int j = 0; j < 2; ++j) {
      const int rr = j * 64 + r0;
      r[j] = __builtin_nontemporal_load(
          (const f4*)(Ap + (size_t)(m0 + rr) * Kj + kk + cf));
    }
  };

  auto loadB = [&](int t) {
    const float* Ap; const u8* Bp; u8* Af8; int Kj, kk;
    tileinfo(t, Ap, Bp, Af8, Kj, kk);
    u8* sB = &lds[(t & 3) * BUFSZ] + ASZ;
    const int off = tid * 16;
    const int r = off >> 6, c = off & 63;
    gload16(Bp + (size_t)r * Kj + kk + (c ^ (((r >> 1) & 3) << 4)), sB + off);
  };

  auto writeA = [&](int t, f4 (&r)[2]) {
    const float* Ap; const u8* Bp; u8* Af8; int Kj, kk;
    tileinfo(t, Ap, Bp, Af8, Kj, kk);
    u8* sA = &lds[(t & 3) * BUFSZ];
#pragma unroll
    for (int j = 0; j < 2; ++j) {
      const int rr = j * 64 + r0;
      const int pw = pk8(r[j][0] * SADJ, r[j][1] * SADJ, r[j][2] * SADJ, r[j][3] * SADJ);
      *(int*)&sA[rr * LDA + cf] = pw;
      *(int*)(Af8 + (size_t)(m0 + rr) * Kj + kk + cf) = pw;
    }
  };

  auto compute = [&](int t) {
    const u8* sA = &lds[(t & 3) * BUFSZ];
    const u8* sB = sA + ASZ;
    __builtin_amdgcn_s_setprio(1);
#pragma unroll
    for (int ks = 0; ks < 2; ++ks) {
      i64 a[2], b[4];
#pragma unroll
      for (int m = 0; m < 2; ++m) {
        const int r = wm + m * 16 + lrow;
        a[m] = *(const i64*)&sA[r * LDA + ks * 32 + lgrp * 8];
      }
#pragma unroll
      for (int n = 0; n < 4; ++n) {
        const int r = wn + n * 16 + lrow;
        b[n] = *(const i64*)&sB[r * BK + ((ks * 32 + lgrp * 8) ^ (((r >> 1) & 3) << 4))];
      }
#pragma unroll
      for (int m = 0; m < 2; ++m)
#pragma unroll
        for (int n = 0; n < 4; ++n)
          acc[m][n] = __builtin_amdgcn_mfma_f32_16x16x32_fp8_fp8(a[m], b[n], acc[m][n], 0, 0, 0);
    }
    __builtin_amdgcn_s_setprio(0);
  };

  auto step = [&](int t, f4 (&rIn)[2], f4 (&rOut)[2]) {
    const bool has_next = (t + 1 < NT);
    if (has_next) { loadA(t + 1, rOut); loadB(t + 1); }
    if (!has_next)   asm volatile("s_waitcnt vmcnt(0)" ::: "memory");
    else if (t == 0) asm volatile("s_waitcnt vmcnt(3)" ::: "memory");
    else             asm volatile("s_waitcnt vmcnt(5)" ::: "memory");
    writeA(t, rIn);
    asm volatile("s_waitcnt lgkmcnt(0)" ::: "memory");
    asm volatile("s_barrier" ::: "memory");
    compute(t);
  };

  loadA(0, rA0); loadB(0);

  for (int t = 0; t < NT; t += 2) {
    step(t, rA0, rA1);
    step(t + 1, rA1, rA0);
  }

  // bf16 partial store
  u16* Cp = Cout + (size_t)z * MN;
#pragma unroll
  for (int n = 0; n < 4; ++n) {
    const int c = wn + n * 16 + lrow;
#pragma unroll
    for (int m = 0; m < 2; ++m) {
      const int rb = m0 + wm + m * 16 + lgrp * 4;
#pragma unroll
      for (int q = 0; q < 4; ++q)
        Cp[(size_t)(rb + q) * 256 + c] = f2b(acc[m][n][q]);
    }
  }
}

// ---------------------------------------------------------------------------
// MERGED fp8 layer-2 big GEMMs (x and y problems in one 1024-block launch).
// Depth-2 counted-vmcnt pipeline, 3 LDS buffers (72 KiB -> 2 blocks/CU).
// Block flat-id swizzled over the full grid, then id<512 -> x else y.
// bf16 partials; setprio around MFMA.
// ---------------------------------------------------------------------------
__global__ __launch_bounds__(256)
void gemm8_k(const u8* __restrict__ xA0, const u8* __restrict__ xA1,
             const u8* __restrict__ xB0, const u8* __restrict__ xB1,
             int xK0, int xK1, int xL0, int xL1, u16* __restrict__ xC, size_t xMN,
             const u8* __restrict__ yA0, const u8* __restrict__ yA1,
             const u8* __restrict__ yB0, const u8* __restrict__ yB1,
             int yK0, int yK1, int yL0, int yL1, u16* __restrict__ yC, size_t yMN)
{
  constexpr int BM = 128, BK = 128, BN = 64;
  constexpr int MR = 4, NR = 2;
  constexpr int ASZ = BM * BK, BSZ = BN * BK;
  __shared__ __align__(16) u8 lds[3 * (ASZ + BSZ)];

  const int tid = threadIdx.x, lane = tid & 63, wave = tid >> 6;
  const int wm = (wave >> 1) * 64, wn = (wave & 1) * 32;
  const int lgrp = lane >> 4, lrow = lane & 15;

  const int flat = blockIdx.x;
  const int nwg = gridDim.x;                       // 1024
  const int swz = (flat & 7) * (nwg >> 3) + (flat >> 3);

  const u8 *A0, *A1, *B0, *B1; int K0, K1, L0, L1; u16* Cw; size_t MN;
  int m0, z;
  if (swz < 512) {
    A0=xA0; A1=xA1; B0=xB0; B1=xB1; K0=xK0; K1=xK1; L0=xL0; L1=xL1; Cw=xC; MN=xMN;
    m0 = (swz & 63) * BM; z = swz >> 6;            // gy=64, z 0..7
  } else {
    const int id = swz - 512;
    A0=yA0; A1=yA1; B0=yB0; B1=yB1; K0=yK0; K1=yK1; L0=yL0; L1=yL1; Cw=yC; MN=yMN;
    m0 = (id & 31) * BM; z = id >> 5;              // gy=32, z 0..15
  }

  const int nt0 = L0 >> 7, NT = nt0 + (L1 >> 7);

  f32x4 acc[MR][NR];
#pragma unroll
  for (int m = 0; m < MR; ++m)
#pragma unroll
    for (int n = 0; n < NR; ++n) acc[m][n] = (f32x4){0.f, 0.f, 0.f, 0.f};

  auto stage = [&](int buf, int t) {
    const u8* Ap; const u8* Bp; int Kj, kk;
    if (t < nt0) { Ap = A0; Bp = B0; Kj = K0; kk = z * L0 + (t << 7); }
    else         { Ap = A1; Bp = B1; Kj = K1; kk = z * L1 + ((t - nt0) << 7); }
    u8* sA = &lds[buf * (ASZ + BSZ)];
    u8* sB = sA + ASZ;
#pragma unroll
    for (int i = 0; i < ASZ / 4096; ++i) {
      const int off = i * 4096 + tid * 16;
      const int r = off >> 7, c = off & 127;
      gload16(Ap + (size_t)(m0 + r) * Kj + kk + (c ^ ((r & 7) << 4)), sA + off);
    }
#pragma unroll
    for (int i = 0; i < BSZ / 4096; ++i) {
      const int off = i * 4096 + tid * 16;
      const int r = off >> 7, c = off & 127;
      gload16(Bp + (size_t)r * Kj + kk + (c ^ ((r & 7) << 4)), sB + off);
    }
  };

  auto compute = [&](int buf) {
    const u8* sA = &lds[buf * (ASZ + BSZ)];
    const u8* sB = sA + ASZ;
    __builtin_amdgcn_s_setprio(1);
#pragma unroll
    for (int ks = 0; ks < 4; ++ks) {
      i64 a[MR], b[NR];
#pragma unroll
      for (int m = 0; m < MR; ++m) {
        const int r = wm + m * 16 + lrow;
        a[m] = *(const i64*)&sA[r * BK + ((ks * 32 + lgrp * 8) ^ ((r & 7) << 4))];
      }
#pragma unroll
      for (int n = 0; n < NR; ++n) {
        const int r = wn + n * 16 + lrow;
        b[n] = *(const i64*)&sB[r * BK + ((ks * 32 + lgrp * 8) ^ ((r & 7) << 4))];
      }
#pragma unroll
      for (int m = 0; m < MR; ++m)
#pragma unroll
        for (int n = 0; n < NR; ++n)
          acc[m][n] = __builtin_amdgcn_mfma_f32_16x16x32_fp8_fp8(a[m], b[n], acc[m][n], 0, 0, 0);
    }
    __builtin_amdgcn_s_setprio(0);
  };

  stage(0, 0);
  stage(1, 1);
  for (int t = 0; t < NT; ++t) {
    if (t + 1 < NT) asm volatile("s_waitcnt vmcnt(6)" ::: "memory");
    else            asm volatile("s_waitcnt vmcnt(0)" ::: "memory");
    asm volatile("s_barrier" ::: "memory");
    compute(t % 3);
    if (t + 2 < NT) stage((t + 2) % 3, t + 2);
  }

  u16* Cp = Cw + (size_t)z * MN;
#pragma unroll
  for (int n = 0; n < NR; ++n) {
    const int c = wn + n * 16 + lrow;
#pragma unroll
    for (int m = 0; m < MR; ++m) {
      const int rb = m0 + wm + m * 16 + lgrp * 4;
#pragma unroll
      for (int q = 0; q < 4; ++q)
        Cp[(size_t)(rb + q) * 64 + c] = f2b(acc[m][n][q]);
    }
  }
}

// ---------------------------------------------------------------------------
// MERGED dual-problem small GEMM (BM=BN=64): blockIdx.y < ySplit -> problem X,
// else problem Y. EPI: fp8 C^T * sOut, split at nsplit output cols.
// ---------------------------------------------------------------------------
template<bool A_F32>
__global__ __launch_bounds__(256)
void gemmS_k(const void* Ax, const u16* Bx, int Kx, int ldcx, u8* Cx1, u8* Cx2,
             const void* Ay, const u16* By, int Ky, int ldcy, u8* Cy1, u8* Cy2,
             int ySplit, int nsplit, float sOut)
{
  constexpr int BM = 64, BN = 64, BK = 32, LD = 40;
  constexpr int MR = 2, NR = 2;
  __shared__ u16 sA[BM * LD];
  __shared__ u16 sB[BN * LD];

  const int tid  = threadIdx.x;
  const int lane = tid & 63;
  const int wave = tid >> 6;
  const int wm = (wave >> 1) * 32;
  const int wn = (wave &  1) * 32;

  const void* A0_; const u16* B0_; int K0, ldc; u8 *C1, *C2; int m0;
  if ((int)blockIdx.y < ySplit) {
    A0_ = Ax; B0_ = Bx; K0 = Kx; ldc = ldcx; C1 = Cx1; C2 = Cx2;
    m0 = blockIdx.y * BM;
  } else {
    A0_ = Ay; B0_ = By; K0 = Ky; ldc = ldcy; C1 = Cy1; C2 = Cy2;
    m0 = (blockIdx.y - ySplit) * BM;
  }
  const int n0 = blockIdx.x * BN;

  constexpr int TPRA = 256 / BM;      // 4
  constexpr int EPTA = 32 / TPRA;     // 8
  const int ar = tid / TPRA, ac = (tid % TPRA) * EPTA;
  const int br = ar, bc = ac;

  f32x4 acc[MR][NR];
#pragma unroll
  for (int m = 0; m < MR; ++m)
#pragma unroll
    for (int n = 0; n < NR; ++n) acc[m][n] = (f32x4){0.f, 0.f, 0.f, 0.f};

  const int lgrp = lane >> 4, lrow = lane & 15;

  for (int kk = 0; kk < K0; kk += BK) {
    if constexpr (A_F32) {
      const float* Ap = (const float*)A0_ + (size_t)(m0 + ar) * K0 + kk + ac;
      f4 v0 = ((const f4*)Ap)[0];
      f4 v1 = ((const f4*)Ap)[1];
      u16x8 h;
      h[0]=f2b(v0[0]); h[1]=f2b(v0[1]); h[2]=f2b(v0[2]); h[3]=f2b(v0[3]);
      h[4]=f2b(v1[0]); h[5]=f2b(v1[1]); h[6]=f2b(v1[2]); h[7]=f2b(v1[3]);
      *(u16x8*)&sA[ar * LD + ac] = h;
    } else {
      const u16* Ap = (const u16*)A0_ + (size_t)(m0 + ar) * K0 + kk + ac;
      *(u16x8*)&sA[ar * LD + ac] = *(const u16x8*)Ap;
    }
    {
      const u16* Bp = B0_ + (size_t)(n0 + br) * K0 + kk + bc;
      *(u16x8*)&sB[br * LD + bc] = *(const u16x8*)Bp;
    }
    __syncthreads();
    bf16x8 af[MR], bfr[NR];
#pragma unroll
    for (int m = 0; m < MR; ++m)
      af[m] = *(const bf16x8*)&sA[(wm + m * 16 + lrow) * LD + lgrp * 8];
#pragma unroll
    for (int n = 0; n < NR; ++n)
      bfr[n] = *(const bf16x8*)&sB[(wn + n * 16 + lrow) * LD + lgrp * 8];
#pragma unroll
    for (int m = 0; m < MR; ++m)
#pragma unroll
      for (int n = 0; n < NR; ++n)
        acc[m][n] = __builtin_amdgcn_mfma_f32_16x16x32_bf16(af[m], bfr[n], acc[m][n], 0, 0, 0);
    __syncthreads();
  }

#pragma unroll
  for (int n = 0; n < NR; ++n) {
    const int c = n0 + wn + n * 16 + lrow;
    u8* Cp = (c < nsplit) ? C1 : C2;
    const int cr = (c < nsplit) ? c : c - nsplit;
#pragma unroll
    for (int m = 0; m < MR; ++m) {
      const int rb = m0 + wm + m * 16 + lgrp * 4;
      int w = __builtin_amdgcn_cvt_pk_fp8_f32(acc[m][n][0] * sOut, acc[m][n][1] * sOut, 0, false);
      w = __builtin_amdgcn_cvt_pk_fp8_f32(acc[m][n][2] * sOut, acc[m][n][3] * sOut, w, true);
      *(int*)&Cp[(size_t)cr * ldc + rb] = w;
    }
  }
}

// ---------------------------------------------------------------------------
// bf16 GEMM for h_hat: EPI sigmoid -> f32 row-major.
// ---------------------------------------------------------------------------
__global__ __launch_bounds__(256)
void gemmH_k(const u16* A0_, const u16* B0_, int K0, float* Cout, int ldc)
{
  constexpr int BM = 128, BN = 128, BK = 32, LD = 40;
  constexpr int MR = 4, NR = 4;
  __shared__ u16 sA[BM * LD];
  __shared__ u16 sB[BN * LD];

  const int tid  = threadIdx.x;
  const int lane = tid & 63;
  const int wave = tid >> 6;
  const int wm = (wave >> 1) * 64;
  const int wn = (wave &  1) * 64;
  const int m0 = blockIdx.y * BM;
  const int n0 = blockIdx.x * BN;

  constexpr int TPRA = 2;             // 256/128
  constexpr int EPTA = 16;
  const int ar = tid / TPRA, ac = (tid % TPRA) * EPTA;

  f32x4 acc[MR][NR];
#pragma unroll
  for (int m = 0; m < MR; ++m)
#pragma unroll
    for (int n = 0; n < NR; ++n) acc[m][n] = (f32x4){0.f, 0.f, 0.f, 0.f};

  const int lgrp = lane >> 4, lrow = lane & 15;

  for (int kk = 0; kk < K0; kk += BK) {
    {
      const u16* Ap = A0_ + (size_t)(m0 + ar) * K0 + kk + ac;
      *(u16x8*)&sA[ar * LD + ac]     = ((const u16x8*)Ap)[0];
      *(u16x8*)&sA[ar * LD + ac + 8] = ((const u16x8*)Ap)[1];
      const u16* Bp = B0_ + (size_t)(n0 + ar) * K0 + kk + ac;
      *(u16x8*)&sB[ar * LD + ac]     = ((const u16x8*)Bp)[0];
      *(u16x8*)&sB[ar * LD + ac + 8] = ((const u16x8*)Bp)[1];
    }
    __syncthreads();
    bf16x8 af[MR], bfr[NR];
#pragma unroll
    for (int m = 0; m < MR; ++m)
      af[m] = *(const bf16x8*)&sA[(wm + m * 16 + lrow) * LD + lgrp * 8];
#pragma unroll
    for (int n = 0; n < NR; ++n)
      bfr[n] = *(const bf16x8*)&sB[(wn + n * 16 + lrow) * LD + lgrp * 8];
#pragma unroll
    for (int m = 0; m < MR; ++m)
#pragma unroll
      for (int n = 0; n < NR; ++n)
        acc[m][n] = __builtin_amdgcn_mfma_f32_16x16x32_bf16(af[m], bfr[n], acc[m][n], 0, 0, 0);
    __syncthreads();
  }

  float* Cp = Cout;
#pragma unroll
  for (int n = 0; n < NR; ++n) {
    const int c = n0 + wn + n * 16 + lrow;
#pragma unroll
    for (int m = 0; m < MR; ++m) {
      const int rb = m0 + wm + m * 16 + lgrp * 4;
#pragma unroll
      for (int q = 0; q < 4; ++q)
        Cp[(size_t)(rb + q) * ldc + c] = 1.f / (1.f + __expf(-acc[m][n][q]));
    }
  }
}

// out[i] = lrelu( invs*sum_z parts_bf16[z][i] + mix*b0[c] + (1-mix)*b1[c] ) -> bf16
__global__ __launch_bounds__(256)
void combine_k(const u16* __restrict__ parts, int KS, int N, size_t MN,
               const float* b0, const float* b1, const float* mixp, u16* out, float invs)
{
  const float mix = *mixp;
  const size_t stride = (size_t)gridDim.x * 1024;
  for (size_t i = ((size_t)blockIdx.x * 256 + threadIdx.x) * 4; i < MN; i += stride) {
    f4 s = {0.f, 0.f, 0.f, 0.f};
    for (int zz = 0; zz < KS; ++zz) {
      u16x4 pv = *(const u16x4*)&parts[(size_t)zz * MN + i];
#pragma unroll
      for (int q = 0; q < 4; ++q) s[q] += b2f(pv[q]);
    }
    const int c = (int)(i % (size_t)N);
    u16x4 o;
#pragma unroll
    for (int q = 0; q < 4; ++q) {
      float v = s[q] * invs + mix * b0[c + q] + (1.f - mix) * b1[c + q];
      v = v >= 0.f ? v : 0.2f * v;
      o[q] = f2b(v);
    }
    *(u16x4*)&out[i] = o;
  }
}

// Concatenated transposed scaled bf16 weights
__global__ __launch_bounds__(256)
void prep_w(const float* Wx1a, const float* Wx1b, const float* Wy1a, const float* Wy1b,
            const float* Wx2a, const float* Wx2b, const float* Wy2a, const float* Wy2b,
            u16* WtX, u16* WtY, u16* W2X, u16* W2Y,
            const float* ap, const float* bp)
{
  const int zz = blockIdx.z;
  const float a = *ap, b = *bp;
  const float* W; u16* O; int K, N, roff; float s;
  switch (zz) {
    case 0: W=Wx1a; O=WtX; K=512; N=256; roff=0;   s=a;      break;
    case 1: W=Wy1b; O=WtX; K=512; N=256; roff=256; s=1.f-b;  break;
    case 2: W=Wx1b; O=WtY; K=256; N=256; roff=0;   s=1.f-a;  break;
    case 3: W=Wy1a; O=WtY; K=256; N=256; roff=256; s=b;      break;
    case 4: W=Wx2a; O=W2X; K=256; N=64;  roff=0;   s=a;      break;
    case 5: W=Wy2b; O=W2X; K=256; N=64;  roff=64;  s=1.f-b;  break;
    case 6: W=Wx2b; O=W2Y; K=256; N=64;  roff=0;   s=1.f-a;  break;
    default:W=Wy2a; O=W2Y; K=256; N=64;  roff=64;  s=b;      break;
  }
  const int total = K * N;
  for (int i = blockIdx.x * 256 + threadIdx.x; i < total; i += gridDim.x * 256) {
    const int k = i / N, n = i - k * N;
    O[(size_t)(n + roff) * K + k] = f2b(W[i] * s);
  }
}

__global__ __launch_bounds__(256)
void softmax_k(const u16* x, float* out)
{
  const int row  = blockIdx.x * 4 + (threadIdx.x >> 6);
  const int lane = threadIdx.x & 63;
  const float v = b2f(x[row * 64 + lane]);
  float m = v;
#pragma unroll
  for (int off = 32; off; off >>= 1) m = fmaxf(m, __shfl_xor(m, off));
  float s = __expf(v - m);
#pragma unroll
  for (int off = 32; off; off >>= 1) s += __shfl_xor(s, off);
  out[(size_t)row * 64 + lane] = v - m - __logf(s);
}

extern "C" void kernel_launch(void* const* d_in, const int* in_sizes, int n_in,
                              void* d_out, int out_size, void* d_ws, size_t ws_size,
                              hipStream_t stream)
{
  const float* hx1 = (const float*)d_in[0];
  const float* hx2 = (const float*)d_in[1];
  const float* x0  = (const float*)d_in[2];
  const float* hy1 = (const float*)d_in[3];
  const float* hy2 = (const float*)d_in[4];
  const float* y0  = (const float*)d_in[5];
  const float* alphap = (const float*)d_in[6];
  const float* betap  = (const float*)d_in[7];
  const float* Wx1a = (const float*)d_in[8];  const float* bx1a = (const float*)d_in[9];
  const float* Wx1b = (const float*)d_in[10]; const float* bx1b = (const float*)d_in[11];
  const float* Wx2a = (const float*)d_in[12]; const float* bx2a = (const float*)d_in[13];
  const float* Wx2b = (const float*)d_in[14]; const float* bx2b = (const float*)d_in[15];
  const float* Wy1a = (const float*)d_in[16]; const float* by1a = (const float*)d_in[17];
  const float* Wy1b = (const float*)d_in[18]; const float* by1b = (const float*)d_in[19];
  const float* Wy2a = (const float*)d_in[20]; const float* by2a = (const float*)d_in[21];
  const float* Wy2b = (const float*)d_in[22]; const float* by2b = (const float*)d_in[23];
  (void)in_sizes; (void)n_in; (void)out_size;

  constexpr int Nx = 8192, Ny = 4096, Fx = 512, Fy = 256, D1 = 256, C = 64;
  constexpr float SB1 = 16.f, SB2 = 256.f;
  constexpr float INV1 = 1.f / (8192.f * 16.f);
  constexpr float INV2 = 1.f / (8192.f * 256.f);
  constexpr int KSx = 4, KSy = 8;

  u8* wsb = (u8*)d_ws;
  size_t off = 0;
  auto alloc = [&](size_t n) { u8* p = wsb + off; off += (n + 63) & ~(size_t)63; return p; };

  u16* WtX = (u16*)alloc((size_t)512 * 512 * 2);
  u16* WtY = (u16*)alloc((size_t)512 * 256 * 2);
  u16* W2X = (u16*)alloc((size_t)128 * 256 * 2);
  u16* W2Y = (u16*)alloc((size_t)128 * 256 * 2);
  u8* B1x  = alloc((size_t)D1 * Nx);
  u8* B2x  = alloc((size_t)D1 * Ny);
  u8* B1y  = alloc((size_t)D1 * Ny);
  u8* B2y  = alloc((size_t)D1 * Nx);
  u16* x1  = (u16*)alloc((size_t)Nx * D1 * 2);
  u16* y1  = (u16*)alloc((size_t)Ny * D1 * 2);
  u8* B1x2 = alloc((size_t)C * Nx);
  u8* B2x2 = alloc((size_t)C * Ny);
  u8* B1y2 = alloc((size_t)C * Ny);
  u8* B2y2 = alloc((size_t)C * Nx);
  u16* x2  = (u16*)alloc((size_t)Nx * C * 2);
  u16* y2  = (u16*)alloc((size_t)Ny * C * 2);

  const size_t base_off = off;
  const size_t szHx1 = (size_t)Nx * Nx, szHx2 = (size_t)Nx * Ny;
  const size_t szHy1 = (size_t)Ny * Ny, szHy2 = (size_t)Ny * Nx;
  const size_t needA = base_off + szHx1 + szHx2 + szHy1 + szHy2 + ((size_t)32 << 20) + (1 << 20);

  u8 *hx1f8, *hx2f8, *hy1f8, *hy2f8; u16* part;
  if (ws_size >= needA) {
    hx1f8 = alloc(szHx1); hx2f8 = alloc(szHx2);
    hy1f8 = alloc(szHy1); hy2f8 = alloc(szHy2);
    part  = (u16*)alloc((size_t)32 << 20);
  } else {
    hy1f8 = alloc(szHy1); hy2f8 = alloc(szHy2);
    hx1f8 = (u8*)d_out;
    hx2f8 = (u8*)d_out + szHx1;
    part  = (u16*)((u8*)d_out + szHx1 + szHx2);
  }

  const size_t MNx1 = (size_t)Nx * D1, MNy1 = (size_t)Ny * D1;
  const size_t MNx2 = (size_t)Nx * C,  MNy2 = (size_t)Ny * C;

  // 1) concat weights
  prep_w<<<dim3(256, 1, 8), 256, 0, stream>>>(Wx1a, Wx1b, Wy1a, Wy1b, Wx2a, Wx2b, Wy2a, Wy2b,
      WtX, WtY, W2X, W2Y, alphap, betap);

  // 2) layer-1 small GEMMs, x+y merged into one launch
  gemmS_k<true><<<dim3(8, Nx/64 + Ny/64), 256, 0, stream>>>(
      x0, WtX, Fx, Nx, B1x, B2y,
      y0, WtY, Fy, Ny, B2x, B1y,
      Nx/64, 256, SB1);

  // 3) layer-1 FUSED big GEMMs + combines (bf16 partials)
  gemmF_k<<<dim3(1, Nx/128, KSx), 1024, 0, stream>>>(hx1, hx2, B1x, B2x, hx1f8, hx2f8,
      Nx, Ny, Nx/KSx, Ny/KSx, part, MNx1);
  combine_k<<<dim3(2048), 256, 0, stream>>>(part, KSx, D1, MNx1, bx1a, bx1b, alphap, x1, INV1);
  gemmF_k<<<dim3(1, Ny/128, KSy), 1024, 0, stream>>>(hy1, hy2, B1y, B2y, hy1f8, hy2f8,
      Ny, Nx, Ny/KSy, Nx/KSy, part, MNy1);
  combine_k<<<dim3(1024), 256, 0, stream>>>(part, KSy, D1, MNy1, by1a, by1b, betap, y1, INV1);

  // 4) layer-2 small GEMMs, merged
  gemmS_k<false><<<dim3(2, Nx/64 + Ny/64), 256, 0, stream>>>(
      x1, W2X, D1, Nx, B1x2, B2y2,
      y1, W2Y, D1, Ny, B2x2, B1y2,
      Nx/64, 64, SB2);

  // 5) layer-2 big GEMMs, x+y merged into one 1024-block launch (bf16 partials)
  u16* partY2 = part + 8 * MNx2;   // x uses 8 slices, y 16 slices after it
  gemm8_k<<<dim3(1024), 256, 0, stream>>>(
      hx1f8, hx2f8, B1x2, B2x2, Nx, Ny, 1024, 512, part, MNx2,
      hy1f8, hy2f8, B1y2, B2y2, Ny, Nx, 256, 512, partY2, MNy2);
  combine_k<<<dim3(512), 256, 0, stream>>>(part, 8, C, MNx2, bx2a, bx2b, alphap, x2, INV2);
  combine_k<<<dim3(256), 256, 0, stream>>>(partY2, 16, C, MNy2, by2a, by2b, betap, y2, INV2);

  // 6) h_hat = sigmoid(x2 @ y2^T) -> d_out
  gemmH_k<<<dim3(Ny/128, Nx/128), 256, 0, stream>>>(x2, y2, C, (float*)d_out, Ny);

  // 7) x_output = log_softmax(x2)
  softmax_k<<<dim3(Nx/4), 256, 0, stream>>>(x2, (float*)d_out + (size_t)Nx * Ny);
}